// Round 1
// baseline (858.500 us; speedup 1.0000x reference)
//
#include <hip/hip_runtime.h>
#include <hip/hip_bf16.h>

typedef __attribute__((ext_vector_type(8))) short short8;
typedef __attribute__((ext_vector_type(4))) float f32x4;
typedef __attribute__((ext_vector_type(4))) int   int4v;

__device__ __forceinline__ short f2bf(float f) {
  unsigned u = __float_as_uint(f);
  u += 0x7fffu + ((u >> 16) & 1u);   // RNE
  return (short)(u >> 16);
}

// ---------------- L2 norm scale: scale[n*P+p] = 1/(||feat0[n,:,p]|| + 1e-10) ----------
__global__ __launch_bounds__(256) void l2norm_kernel(const float* __restrict__ f0,
                                                     float* __restrict__ scale,
                                                     int C, int P, int total) {
  __shared__ float red[4][64];
  int pl = threadIdx.x & 63;
  int cg = threadIdx.x >> 6;
  int pos = blockIdx.x * 64 + pl;
  float s = 0.f;
  if (pos < total) {
    int n = pos / P, sp = pos - n * P;
    const float* base = f0 + (size_t)n * C * P + sp;
    int c0 = cg * (C >> 2), c1 = c0 + (C >> 2);
    for (int c = c0; c < c1; ++c) {
      float v = base[(size_t)c * P];
      s += v * v;
    }
  }
  red[cg][pl] = s;
  __syncthreads();
  if (threadIdx.x < 64 && pos < total) {
    float tot = red[0][pl] + red[1][pl] + red[2][pl] + red[3][pl];
    scale[pos] = 1.0f / (sqrtf(tot) + 1e-10f);
  }
}

// ---------------- NCHW fp32 -> NHWC bf16 (optional per-pos scale, per-ch weight) ------
__global__ __launch_bounds__(256) void to_nhwc_kernel(const float* __restrict__ src,
    short* __restrict__ dst, const float* __restrict__ rowscale,
    const float* __restrict__ chw, int C, int P) {
  __shared__ float tile[32][33];
  int n = blockIdx.z;
  int p0 = blockIdx.x * 32, c0 = blockIdx.y * 32;
  int tp = threadIdx.x & 31, tr = threadIdx.x >> 5;
  const float* s = src + (size_t)n * C * P;
  #pragma unroll
  for (int i = 0; i < 4; ++i) {
    int cl = tr + i * 8;
    int p = p0 + tp;
    tile[cl][tp] = (p < P) ? s[(size_t)(c0 + cl) * P + p] : 0.f;
  }
  __syncthreads();
  #pragma unroll
  for (int i = 0; i < 4; ++i) {
    int pl = tr + i * 8;
    int p = p0 + pl;
    if (p >= P) continue;
    int c = c0 + tp;
    float v = tile[tp][pl];
    if (chw)      v *= chw[c];
    if (rowscale) v *= rowscale[n * P + p];
    dst[(size_t)(n * P + p) * C + c] = f2bf(v);
  }
}

// ---------------- weight repack: (Co,Ci,S) fp32 -> [co][s][ci] bf16 -------------------
struct WSeg { const float* src; short* dst; int Ci; int S; int elems; };
struct WPrep { WSeg seg[20]; };

__global__ __launch_bounds__(256) void wprep_kernel(WPrep p, int total) {
  int i = blockIdx.x * 256 + threadIdx.x;
  if (i >= total) return;
  int local = i;
  int si = 0;
  while (local >= p.seg[si].elems) { local -= p.seg[si].elems; ++si; }
  WSeg sg = p.seg[si];
  int ci = local % sg.Ci;
  int q  = local / sg.Ci;
  int s  = q % sg.S;
  int co = q / sg.S;
  float v = sg.src[((size_t)co * sg.Ci + ci) * sg.S + s];
  sg.dst[local] = f2bf(v);
}

// ---------------- generic implicit-GEMM conv, bf16 MFMA ------------------------------
struct ConvP {
  const short* in;   // bf16 NHWC [16][Hi][Wi][Ci]
  const short* w;    // bf16 [Co][S][Ci]
  const float* b1;   // bias (extra) / cls bias (head)
  const float* b2;   // box bias (head)
  short* out_bf;     // extra: bf16 NHWC out
  float* out_f;      // head: packed d_out
  int M, Ci, Hi, Wi, Ho, Wo, Co;
  int S, kdim, stride, pad;
  int mbox, row_base;
};

template<bool HEAD>
__global__ __launch_bounds__(256) void conv_gemm(ConvP p) {
  __shared__ short As[64 * 40];
  __shared__ short Bs[64 * 40];
  int t = threadIdx.x;
  int srow = t >> 2;            // 0..63 staging row
  int skc  = (t & 3) << 3;      // k-chunk 0/8/16/24
  int HW = p.Ho * p.Wo;
  int pos = blockIdx.x * 64 + srow;
  int n = pos / HW, rem = pos - n * HW;
  int yo = rem / p.Wo, xo = rem - yo * p.Wo;
  bool mvalid = pos < p.M;
  int co_s = blockIdx.y * 64 + srow;
  bool nvalid = co_s < p.Co;
  const short* wrow  = p.w + (size_t)co_s * p.S * p.Ci;
  const short* abase = p.in + (size_t)n * p.Hi * p.Wi * p.Ci;

  f32x4 acc[2][2];
  #pragma unroll
  for (int i = 0; i < 2; ++i)
    #pragma unroll
    for (int j = 0; j < 2; ++j)
      acc[i][j] = (f32x4){0.f, 0.f, 0.f, 0.f};

  int lane = t & 63, wave = t >> 6;
  int wr = (wave >> 1) * 32, wc = (wave & 1) * 32;
  int lrow = lane & 15;
  int lk = (lane >> 4) << 3;
  const short* a_lds = &As[(wr + lrow) * 40 + lk];
  const short* b_lds = &Bs[(wc + lrow) * 40 + lk];

  for (int s = 0; s < p.S; ++s) {
    int dy = s / p.kdim, dx = s - dy * p.kdim;
    int iy = yo * p.stride + dy - p.pad;
    int ix = xo * p.stride + dx - p.pad;
    bool svalid = mvalid && iy >= 0 && iy < p.Hi && ix >= 0 && ix < p.Wi;
    const short* arow = abase + (ptrdiff_t)(iy * p.Wi + ix) * p.Ci;
    const short* wsub = wrow + s * p.Ci;
    for (int c0 = 0; c0 < p.Ci; c0 += 32) {
      __syncthreads();
      int4v av = 0, bv = 0;
      if (svalid) av = *reinterpret_cast<const int4v*>(arow + c0 + skc);
      if (nvalid) bv = *reinterpret_cast<const int4v*>(wsub + c0 + skc);
      *reinterpret_cast<int4v*>(&As[srow * 40 + skc]) = av;
      *reinterpret_cast<int4v*>(&Bs[srow * 40 + skc]) = bv;
      __syncthreads();
      short8 a0 = *reinterpret_cast<const short8*>(a_lds);
      short8 a1 = *reinterpret_cast<const short8*>(a_lds + 16 * 40);
      short8 b0 = *reinterpret_cast<const short8*>(b_lds);
      short8 b1 = *reinterpret_cast<const short8*>(b_lds + 16 * 40);
      acc[0][0] = __builtin_amdgcn_mfma_f32_16x16x32_bf16(a0, b0, acc[0][0], 0, 0, 0);
      acc[0][1] = __builtin_amdgcn_mfma_f32_16x16x32_bf16(a0, b1, acc[0][1], 0, 0, 0);
      acc[1][0] = __builtin_amdgcn_mfma_f32_16x16x32_bf16(a1, b0, acc[1][0], 0, 0, 0);
      acc[1][1] = __builtin_amdgcn_mfma_f32_16x16x32_bf16(a1, b1, acc[1][1], 0, 0, 0);
    }
  }

  int mk = p.mbox * 81;
  #pragma unroll
  for (int i = 0; i < 2; ++i)
    #pragma unroll
    for (int j = 0; j < 2; ++j)
      #pragma unroll
      for (int q = 0; q < 4; ++q) {
        int r = wr + i * 16 + ((lane >> 4) << 2) + q;
        int c = wc + j * 16 + (lane & 15);
        int po = blockIdx.x * 64 + r;
        int co = blockIdx.y * 64 + c;
        if (po >= p.M || co >= p.Co) continue;
        float v = acc[i][j][q];
        if (!HEAD) {
          v += p.b1[co];
          v = fmaxf(v, 0.f);
          p.out_bf[(size_t)po * p.Co + co] = f2bf(v);
        } else {
          int n2 = po / HW, sp = po - n2 * HW;
          int mi, col; float bias;
          if (co < mk) { mi = co / 81; col = co - mi * 81; bias = p.b1[co]; }
          else { int cbx = co - mk; mi = cbx >> 2; col = 81 + (cbx & 3); bias = p.b2[cbx]; }
          size_t orow = (size_t)n2 * 8732 + p.row_base + (size_t)sp * p.mbox + mi;
          p.out_f[orow * 85 + col] = v + bias;
        }
      }
}

extern "C" void kernel_launch(void* const* d_in, const int* in_sizes, int n_in,
                              void* d_out, int out_size, void* d_ws, size_t ws_size,
                              hipStream_t stream) {
  const float* feat0 = (const float*)d_in[0];
  const float* feat1 = (const float*)d_in[1];
  const float* l2w   = (const float*)d_in[2];
  const float* ew[8]; const float* eb[8];
  for (int i = 0; i < 8; ++i) { ew[i] = (const float*)d_in[3 + 2 * i]; eb[i] = (const float*)d_in[4 + 2 * i]; }
  const float* cw[6]; const float* cb[6]; const float* bw[6]; const float* bb[6];
  for (int i = 0; i < 6; ++i) {
    cw[i] = (const float*)d_in[19 + 4 * i]; cb[i] = (const float*)d_in[20 + 4 * i];
    bw[i] = (const float*)d_in[21 + 4 * i]; bb[i] = (const float*)d_in[22 + 4 * i];
  }
  float* out = (float*)d_out;
  char* ws = (char*)d_ws;
  size_t off = 0;
  auto alloc = [&](size_t bytes) -> char* {
    char* p = ws + off;
    off = (off + bytes + 255) & ~(size_t)255;
    return p;
  };
  float* scale0 = (float*)alloc(23104 * 4);
  short* f0b = (short*)alloc((size_t)16 * 1444 * 512 * 2);
  short* f1b = (short*)alloc((size_t)16 * 361 * 1024 * 2);
  short* xe0 = (short*)alloc((size_t)16 * 361 * 256 * 2);
  short* f2b = (short*)alloc((size_t)16 * 100 * 512 * 2);
  short* xe2 = (short*)alloc((size_t)16 * 100 * 128 * 2);
  short* f3b = (short*)alloc((size_t)16 * 25 * 256 * 2);
  short* xe4 = (short*)alloc((size_t)16 * 25 * 128 * 2);
  short* f4b = (short*)alloc((size_t)16 * 9 * 256 * 2);
  short* xe6 = (short*)alloc((size_t)16 * 9 * 128 * 2);
  short* f5b = (short*)alloc((size_t)16 * 1 * 256 * 2);

  static const int eCo[8] = {256, 512, 128, 256, 128, 256, 128, 256};
  static const int eCi[8] = {1024, 256, 512, 128, 256, 128, 256, 128};
  static const int eS[8]  = {1, 9, 1, 9, 1, 9, 1, 9};
  static const int mbox[6] = {4, 6, 6, 6, 4, 4};
  static const int hCi[6] = {512, 1024, 512, 256, 256, 256};

  WPrep wp; int total = 0; int segi = 0;
  short* ewb[8]; short* hwb[6];
  for (int i = 0; i < 8; ++i) {
    int e = eCo[i] * eCi[i] * eS[i];
    ewb[i] = (short*)alloc((size_t)e * 2);
    wp.seg[segi++] = {ew[i], ewb[i], eCi[i], eS[i], e};
    total += e;
  }
  for (int L = 0; L < 6; ++L) {
    int co = mbox[L] * 85;
    int e = co * hCi[L] * 9;
    hwb[L] = (short*)alloc((size_t)e * 2);
    int ecls = mbox[L] * 81 * hCi[L] * 9;
    wp.seg[segi++] = {cw[L], hwb[L], hCi[L], 9, ecls};
    wp.seg[segi++] = {bw[L], hwb[L] + (size_t)mbox[L] * 81 * 9 * hCi[L], hCi[L], 9, e - ecls};
    total += e;
  }

  l2norm_kernel<<<dim3((23104 + 63) / 64), 256, 0, stream>>>(feat0, scale0, 512, 1444, 23104);
  to_nhwc_kernel<<<dim3(46, 16, 16), 256, 0, stream>>>(feat0, f0b, scale0, l2w, 512, 1444);
  to_nhwc_kernel<<<dim3(12, 32, 16), 256, 0, stream>>>(feat1, f1b, nullptr, nullptr, 1024, 361);
  wprep_kernel<<<dim3((total + 255) / 256), 256, 0, stream>>>(wp, total);

  auto conv = [&](const short* in, short* wbuf, const float* bias, short* outb,
                  int Ci, int Hi, int Wi, int Ho, int Wo, int Co, int S, int kd, int st, int pad) {
    ConvP p{}; p.in = in; p.w = wbuf; p.b1 = bias; p.b2 = nullptr; p.out_bf = outb; p.out_f = nullptr;
    p.M = 16 * Ho * Wo; p.Ci = Ci; p.Hi = Hi; p.Wi = Wi; p.Ho = Ho; p.Wo = Wo; p.Co = Co;
    p.S = S; p.kdim = kd; p.stride = st; p.pad = pad; p.mbox = 0; p.row_base = 0;
    conv_gemm<false><<<dim3((p.M + 63) / 64, (Co + 63) / 64), 256, 0, stream>>>(p);
  };
  conv(f1b, ewb[0], eb[0], xe0, 1024, 19, 19, 19, 19, 256, 1, 1, 1, 0);
  conv(xe0, ewb[1], eb[1], f2b,  256, 19, 19, 10, 10, 512, 9, 3, 2, 1);
  conv(f2b, ewb[2], eb[2], xe2,  512, 10, 10, 10, 10, 128, 1, 1, 1, 0);
  conv(xe2, ewb[3], eb[3], f3b,  128, 10, 10,  5,  5, 256, 9, 3, 2, 1);
  conv(f3b, ewb[4], eb[4], xe4,  256,  5,  5,  5,  5, 128, 1, 1, 1, 0);
  conv(xe4, ewb[5], eb[5], f4b,  128,  5,  5,  3,  3, 256, 9, 3, 1, 0);
  conv(f4b, ewb[6], eb[6], xe6,  256,  3,  3,  3,  3, 128, 1, 1, 1, 0);
  conv(xe6, ewb[7], eb[7], f5b,  128,  3,  3,  1,  1, 256, 9, 3, 1, 0);

  auto head = [&](const short* in, short* wbuf, const float* cbias, const float* bbias,
                  int Ci, int Hs, int m, int rb) {
    ConvP p{}; p.in = in; p.w = wbuf; p.b1 = cbias; p.b2 = bbias; p.out_bf = nullptr; p.out_f = out;
    p.M = 16 * Hs * Hs; p.Ci = Ci; p.Hi = Hs; p.Wi = Hs; p.Ho = Hs; p.Wo = Hs; p.Co = m * 85;
    p.S = 9; p.kdim = 3; p.stride = 1; p.pad = 1; p.mbox = m; p.row_base = rb;
    conv_gemm<true><<<dim3((p.M + 63) / 64, (p.Co + 63) / 64), 256, 0, stream>>>(p);
  };
  head(f0b, hwb[0], cb[0], bb[0],  512, 38, 4, 0);
  head(f1b, hwb[1], cb[1], bb[1], 1024, 19, 6, 5776);
  head(f2b, hwb[2], cb[2], bb[2],  512, 10, 6, 7942);
  head(f3b, hwb[3], cb[3], bb[3],  256,  5, 6, 8542);
  head(f4b, hwb[4], cb[4], bb[4],  256,  3, 4, 8692);
  head(f5b, hwb[5], cb[5], bb[5],  256,  1, 4, 8728);
}